// Round 1
// baseline (1997.592 us; speedup 1.0000x reference)
//
#include <hip/hip_runtime.h>

// CausalAttention: B=4, S=4096, D_IN=D_OUT=1024, fp32 in/out, bf16 MFMA compute.
//
// Pipeline: convert x->bf16; transpose W->Wt[n][k] bf16; QKV GEMM (128x128 tile,
// MFMA 16x16x32 bf16, V written transposed [d][s]); flash attention with online
// softmax (waves split D=1024 into 8 slices of 128; QK^T partials reduced via
// LDS atomicAdd; P staged bf16 in LDS; PV accumulates per-wave O slice).
//
// Fragment layouts (HW-verified, learn_hip m89/m91/m120):
//   A[m = lane&15][k = (lane>>4)*8 + j]
//   B[k = (lane>>4)*8 + j][n = lane&15]
//   D[row = (lane>>4)*4 + r][col = lane&15]

typedef __attribute__((ext_vector_type(8))) short bh8;
typedef __attribute__((ext_vector_type(4))) float f32x4;
typedef __attribute__((ext_vector_type(4))) unsigned int u32x4;
typedef __attribute__((ext_vector_type(2))) unsigned int u32x2;

#define BATCH 4
#define SEQ   4096
#define DIM   1024
#define MTOT  (BATCH * SEQ)   // 16384

__device__ __forceinline__ unsigned short f2bf(float f) {
  union { float f; unsigned int u; } v; v.f = f;
  return (unsigned short)((v.u + 0x7FFFu + ((v.u >> 16) & 1u)) >> 16);  // RNE
}

// ---------------- kernel 1: x fp32 -> bf16 ----------------
__global__ __launch_bounds__(256)
void k_convert_x(const float* __restrict__ x, unsigned short* __restrict__ xb) {
  size_t idx = ((size_t)blockIdx.x * 256 + threadIdx.x) * 8;
  f32x4 v0 = *(const f32x4*)(x + idx);
  f32x4 v1 = *(const f32x4*)(x + idx + 4);
  u32x4 pk;
  pk[0] = (unsigned)f2bf(v0[0]) | ((unsigned)f2bf(v0[1]) << 16);
  pk[1] = (unsigned)f2bf(v0[2]) | ((unsigned)f2bf(v0[3]) << 16);
  pk[2] = (unsigned)f2bf(v1[0]) | ((unsigned)f2bf(v1[1]) << 16);
  pk[3] = (unsigned)f2bf(v1[2]) | ((unsigned)f2bf(v1[3]) << 16);
  *(u32x4*)(xb + idx) = pk;
}

// ---------------- kernel 2: W[k][n] fp32 -> Wt[n][k] bf16 (x3) ----------------
__global__ __launch_bounds__(256)
void k_transpose_w(const float* __restrict__ Wq, const float* __restrict__ Wk,
                   const float* __restrict__ Wv, unsigned short* __restrict__ wt) {
  __shared__ float tile[32][33];
  const int z = blockIdx.z;
  const float* W = (z == 0) ? Wq : ((z == 1) ? Wk : Wv);
  unsigned short* out = wt + (size_t)z * DIM * DIM;
  const int tx = threadIdx.x, ty = threadIdx.y;
  const int n = blockIdx.x * 32 + tx;
  const int k = blockIdx.y * 32 + ty;
#pragma unroll
  for (int i = 0; i < 32; i += 8)
    tile[ty + i][tx] = W[(size_t)(k + i) * DIM + n];
  __syncthreads();
  const int k2 = blockIdx.y * 32 + tx;
  const int n2 = blockIdx.x * 32 + ty;
#pragma unroll
  for (int i = 0; i < 32; i += 8)
    out[(size_t)(n2 + i) * DIM + k2] = f2bf(tile[tx][ty + i]);
}

// ---------------- kernel 3: QKV GEMM ----------------
// C[16384,1024] = xb @ W   (z=0 -> qb, z=1 -> kb, z=2 -> vt transposed [b][d][s])
__global__ __launch_bounds__(256)
void k_qkv_gemm(const unsigned short* __restrict__ xb, const unsigned short* __restrict__ wt,
                unsigned short* __restrict__ qb, unsigned short* __restrict__ kb,
                unsigned short* __restrict__ vt) {
  const int tid = threadIdx.x;
  const int l = tid & 63, w = tid >> 6;
  const int lane16 = l & 15, quad = l >> 4;
  const int wm = w & 1, wn = w >> 1;
  const int m0 = blockIdx.x * 128, n0 = blockIdx.y * 128, z = blockIdx.z;
  const unsigned short* wtz = wt + (size_t)z * DIM * DIM;

  // pad to 40 shorts (80B row stride -> 2-way LDS conflict = free)
  __shared__ unsigned short As[128][40];
  __shared__ unsigned short Bs[128][40];

  f32x4 acc[4][4];
#pragma unroll
  for (int i = 0; i < 4; ++i)
#pragma unroll
    for (int j = 0; j < 4; ++j) acc[i][j] = (f32x4){0.f, 0.f, 0.f, 0.f};

  for (int k0 = 0; k0 < DIM; k0 += 32) {
#pragma unroll
    for (int i = 0; i < 2; ++i) {
      int c = tid + i * 256;
      int row = c >> 2, cc = (c & 3) * 8;
      *(bh8*)&As[row][cc] = *(const bh8*)(xb  + (size_t)(m0 + row) * DIM + k0 + cc);
      *(bh8*)&Bs[row][cc] = *(const bh8*)(wtz + (size_t)(n0 + row) * DIM + k0 + cc);
    }
    __syncthreads();
    bh8 a[4], b[4];
#pragma unroll
    for (int mt = 0; mt < 4; ++mt) a[mt] = *(const bh8*)&As[wm * 64 + mt * 16 + lane16][quad * 8];
#pragma unroll
    for (int nt = 0; nt < 4; ++nt) b[nt] = *(const bh8*)&Bs[wn * 64 + nt * 16 + lane16][quad * 8];
#pragma unroll
    for (int mt = 0; mt < 4; ++mt)
#pragma unroll
      for (int nt = 0; nt < 4; ++nt)
        acc[mt][nt] = __builtin_amdgcn_mfma_f32_16x16x32_bf16(a[mt], b[nt], acc[mt][nt], 0, 0, 0);
    __syncthreads();
  }

  if (z < 2) {
    unsigned short* outp = (z == 0) ? qb : kb;
#pragma unroll
    for (int mt = 0; mt < 4; ++mt)
#pragma unroll
      for (int nt = 0; nt < 4; ++nt) {
        int row = m0 + wm * 64 + mt * 16 + quad * 4;
        int col = n0 + wn * 64 + nt * 16 + lane16;
#pragma unroll
        for (int r = 0; r < 4; ++r)
          outp[(size_t)(row + r) * DIM + col] = f2bf(acc[mt][nt][r]);
      }
  } else {
    // V transposed: vt[b][d][s]; 4 consecutive s per lane -> 8B store
#pragma unroll
    for (int mt = 0; mt < 4; ++mt)
#pragma unroll
      for (int nt = 0; nt < 4; ++nt) {
        int m = m0 + wm * 64 + mt * 16 + quad * 4;
        int bb = m >> 12, s = m & (SEQ - 1);
        int col = n0 + wn * 64 + nt * 16 + lane16;
        unsigned long long pk =
            (unsigned long long)f2bf(acc[mt][nt][0]) |
            ((unsigned long long)f2bf(acc[mt][nt][1]) << 16) |
            ((unsigned long long)f2bf(acc[mt][nt][2]) << 32) |
            ((unsigned long long)f2bf(acc[mt][nt][3]) << 48);
        *(unsigned long long*)(vt + (size_t)bb * DIM * SEQ + (size_t)col * SEQ + s) = pk;
      }
  }
}

// ---------------- kernel 4: causal flash attention ----------------
// Block: 512 threads (8 waves), each wave owns a 128-wide D slice.
// Each block processes q-tiles {p, 127-p} of 32 rows (load balance).
__global__ __launch_bounds__(512, 2)
void k_attn(const unsigned short* __restrict__ qb, const unsigned short* __restrict__ kb,
            const unsigned short* __restrict__ vt, float* __restrict__ out) {
  const int tid = threadIdx.x;
  const int w = tid >> 6;
  const int l = tid & 63;
  const int lane16 = l & 15, quad = l >> 4;
  const int batch = blockIdx.y;
  const int pid = blockIdx.x;  // 0..63

  __shared__ float Ssh[32][68];            // stride 68 -> 2-way atomics (free)
  __shared__ unsigned short Psh[32][72];   // stride 72 -> 2-way b128 reads
  __shared__ float row_m[32], row_l[32], row_alpha[32];

  const size_t bbase = (size_t)batch * SEQ;
  const unsigned short* vtb = vt + (size_t)batch * DIM * SEQ;
  const float cexp = 0.04508422002778f;  // log2(e)/sqrt(1024)

  for (int half = 0; half < 2; ++half) {
    const int t = (half == 0) ? pid : (127 - pid);
    const int q0 = t * 32;

    // Q fragments for this wave's D slice, held in registers for all k-iters
    bh8 qf[2][4];
#pragma unroll
    for (int mt = 0; mt < 2; ++mt)
#pragma unroll
      for (int c = 0; c < 4; ++c)
        qf[mt][c] = *(const bh8*)(qb + (bbase + q0 + mt * 16 + lane16) * DIM +
                                  w * 128 + c * 32 + quad * 8);

    f32x4 o[2][8];
#pragma unroll
    for (int mt = 0; mt < 2; ++mt)
#pragma unroll
      for (int nt = 0; nt < 8; ++nt) o[mt][nt] = (f32x4){0.f, 0.f, 0.f, 0.f};

    const int nk = (q0 + 95) >> 6;  // ceil((q0+32)/64)
    for (int it = 0; it < nk; ++it) {
      const int k0 = it * 64;
      {
        int r = tid >> 4, c0 = (tid & 15) * 4;
        *(f32x4*)&Ssh[r][c0] = (f32x4){0.f, 0.f, 0.f, 0.f};
        if (it == 0 && tid < 32) { row_m[tid] = -3.0e38f; row_l[tid] = 0.f; }
      }
      __syncthreads();

      // QK^T: partial scores over this wave's 128 D dims -> LDS atomic reduce
#pragma unroll
      for (int kt = 0; kt < 4; ++kt) {
        if (k0 + kt * 16 <= q0 + 31) {  // uniform causal skip
          bh8 kf[4];
#pragma unroll
          for (int c = 0; c < 4; ++c)
            kf[c] = *(const bh8*)(kb + (bbase + k0 + kt * 16 + lane16) * DIM +
                                  w * 128 + c * 32 + quad * 8);
#pragma unroll
          for (int mt = 0; mt < 2; ++mt) {
            f32x4 s = (f32x4){0.f, 0.f, 0.f, 0.f};
#pragma unroll
            for (int c = 0; c < 4; ++c)
              s = __builtin_amdgcn_mfma_f32_16x16x32_bf16(qf[mt][c], kf[c], s, 0, 0, 0);
            int row = mt * 16 + quad * 4;
            int col = kt * 16 + lane16;
#pragma unroll
            for (int r = 0; r < 4; ++r)
              atomicAdd(&Ssh[row + r][col], s[r]);
          }
        }
      }
      __syncthreads();

      // online softmax: thread -> (row = tid>>4, cols = (tid&15)*4 .. +3)
      {
        int r = tid >> 4, c0 = (tid & 15) * 4;
        int q = q0 + r;
        f32x4 sv = *(const f32x4*)&Ssh[r][c0];
#pragma unroll
        for (int j = 0; j < 4; ++j)
          if (k0 + c0 + j > q) sv[j] = -3.0e38f;
        float mx = fmaxf(fmaxf(sv[0], sv[1]), fmaxf(sv[2], sv[3]));
#pragma unroll
        for (int off = 1; off < 16; off <<= 1)
          mx = fmaxf(mx, __shfl_xor(mx, off));
        float mold = row_m[r];
        float mnew = fmaxf(mold, mx);
        float p0 = exp2f((sv[0] - mnew) * cexp);
        float p1 = exp2f((sv[1] - mnew) * cexp);
        float p2 = exp2f((sv[2] - mnew) * cexp);
        float p3 = exp2f((sv[3] - mnew) * cexp);
        float sum = (p0 + p1) + (p2 + p3);
#pragma unroll
        for (int off = 1; off < 16; off <<= 1)
          sum += __shfl_xor(sum, off);
        float alpha = exp2f((mold - mnew) * cexp);
        u32x2 pk;
        pk[0] = (unsigned)f2bf(p0) | ((unsigned)f2bf(p1) << 16);
        pk[1] = (unsigned)f2bf(p2) | ((unsigned)f2bf(p3) << 16);
        *(u32x2*)&Psh[r][c0] = pk;
        if ((tid & 15) == 0) {
          row_m[r] = mnew;
          row_l[r] = alpha * row_l[r] + sum;
          row_alpha[r] = alpha;
        }
      }
      __syncthreads();

      // rescale O, then PV over this wave's 128 output columns
      {
#pragma unroll
        for (int mt = 0; mt < 2; ++mt) {
          f32x4 al;
#pragma unroll
          for (int r = 0; r < 4; ++r) al[r] = row_alpha[mt * 16 + quad * 4 + r];
#pragma unroll
          for (int nt = 0; nt < 8; ++nt) o[mt][nt] *= al;
        }
        bh8 pf[2][2];
#pragma unroll
        for (int mt = 0; mt < 2; ++mt)
#pragma unroll
          for (int kc = 0; kc < 2; ++kc)
            pf[mt][kc] = *(const bh8*)&Psh[mt * 16 + lane16][kc * 32 + quad * 8];
#pragma unroll
        for (int kc = 0; kc < 2; ++kc) {
          if (k0 + kc * 32 <= q0 + 31) {  // uniform: P block all-zero beyond diag
#pragma unroll
            for (int nt = 0; nt < 8; ++nt) {
              bh8 vf = *(const bh8*)(vtb + (size_t)(w * 128 + nt * 16 + lane16) * SEQ +
                                     k0 + kc * 32 + quad * 8);
#pragma unroll
              for (int mt = 0; mt < 2; ++mt)
                o[mt][nt] = __builtin_amdgcn_mfma_f32_16x16x32_bf16(pf[mt][kc], vf, o[mt][nt], 0, 0, 0);
            }
          }
        }
      }
      __syncthreads();
    }

    // epilogue: O / l -> fp32 out
#pragma unroll
    for (int mt = 0; mt < 2; ++mt) {
      int row = mt * 16 + quad * 4;
      float il[4];
#pragma unroll
      for (int r = 0; r < 4; ++r) il[r] = 1.0f / row_l[row + r];
#pragma unroll
      for (int nt = 0; nt < 8; ++nt) {
        size_t base = (bbase + q0 + row) * DIM + w * 128 + nt * 16 + lane16;
#pragma unroll
        for (int r = 0; r < 4; ++r)
          out[base + (size_t)r * DIM] = o[mt][nt][r] * il[r];
      }
    }
    __syncthreads();  // protect row_l / LDS before next tile's init
  }
}

// ---------------- launch ----------------
extern "C" void kernel_launch(void* const* d_in, const int* in_sizes, int n_in,
                              void* d_out, int out_size, void* d_ws, size_t ws_size,
                              hipStream_t stream) {
  const float* x  = (const float*)d_in[0];
  const float* Wq = (const float*)d_in[1];
  const float* Wk = (const float*)d_in[2];
  const float* Wv = (const float*)d_in[3];
  float* out = (float*)d_out;

  char* ws = (char*)d_ws;
  const size_t XB_BYTES = (size_t)MTOT * DIM * 2;        // 32 MB
  const size_t WT_BYTES = (size_t)3 * DIM * DIM * 2;     // 6 MB
  unsigned short* xb = (unsigned short*)(ws);
  unsigned short* wt = (unsigned short*)(ws + XB_BYTES);
  unsigned short* qb = (unsigned short*)(ws + XB_BYTES + WT_BYTES);
  unsigned short* kb = qb + (size_t)MTOT * DIM;
  unsigned short* vt = kb + (size_t)MTOT * DIM;
  // total ws use: 32 + 6 + 3*32 = 134 MB

  k_convert_x<<<dim3((MTOT * DIM) / (256 * 8)), dim3(256), 0, stream>>>(x, xb);
  k_transpose_w<<<dim3(32, 32, 3), dim3(32, 8), 0, stream>>>(Wq, Wk, Wv, wt);
  k_qkv_gemm<<<dim3(MTOT / 128, DIM / 128, 3), dim3(256), 0, stream>>>(xb, wt, qb, kb, vt);
  k_attn<<<dim3(64, BATCH), dim3(512), 0, stream>>>(qb, kb, vt, out);
}

// Round 2
// 908.458 us; speedup vs baseline: 2.1989x; 2.1989x over previous
//
#include <hip/hip_runtime.h>

// CausalAttention: B=4, S=4096, D_IN=D_OUT=1024, fp32 in/out, bf16 MFMA compute.
//
// R2: k_attn restructured — no LDS atomics (per-wave partial buffers + read-reduce
// in softmax), software-pipelined K/V global loads, 2 barriers/iter (was 4),
// XCD-affine grid (batch on blockIdx.x).
//
// Fragment layouts (HW-verified, learn_hip m89/m91/m120):
//   A[m = lane&15][k = (lane>>4)*8 + j]
//   B[k = (lane>>4)*8 + j][n = lane&15]
//   D[row = (lane>>4)*4 + r][col = lane&15]

typedef __attribute__((ext_vector_type(8))) short bh8;
typedef __attribute__((ext_vector_type(4))) float f32x4;
typedef __attribute__((ext_vector_type(4))) unsigned int u32x4;
typedef __attribute__((ext_vector_type(2))) unsigned int u32x2;

#define BATCH 4
#define SEQ   4096
#define DIM   1024
#define MTOT  (BATCH * SEQ)   // 16384

__device__ __forceinline__ unsigned short f2bf(float f) {
  union { float f; unsigned int u; } v; v.f = f;
  return (unsigned short)((v.u + 0x7FFFu + ((v.u >> 16) & 1u)) >> 16);  // RNE
}

// ---------------- kernel 1: x fp32 -> bf16 ----------------
__global__ __launch_bounds__(256)
void k_convert_x(const float* __restrict__ x, unsigned short* __restrict__ xb) {
  size_t idx = ((size_t)blockIdx.x * 256 + threadIdx.x) * 8;
  f32x4 v0 = *(const f32x4*)(x + idx);
  f32x4 v1 = *(const f32x4*)(x + idx + 4);
  u32x4 pk;
  pk[0] = (unsigned)f2bf(v0[0]) | ((unsigned)f2bf(v0[1]) << 16);
  pk[1] = (unsigned)f2bf(v0[2]) | ((unsigned)f2bf(v0[3]) << 16);
  pk[2] = (unsigned)f2bf(v1[0]) | ((unsigned)f2bf(v1[1]) << 16);
  pk[3] = (unsigned)f2bf(v1[2]) | ((unsigned)f2bf(v1[3]) << 16);
  *(u32x4*)(xb + idx) = pk;
}

// ---------------- kernel 2: W[k][n] fp32 -> Wt[n][k] bf16 (x3) ----------------
__global__ __launch_bounds__(256)
void k_transpose_w(const float* __restrict__ Wq, const float* __restrict__ Wk,
                   const float* __restrict__ Wv, unsigned short* __restrict__ wt) {
  __shared__ float tile[32][33];
  const int z = blockIdx.z;
  const float* W = (z == 0) ? Wq : ((z == 1) ? Wk : Wv);
  unsigned short* out = wt + (size_t)z * DIM * DIM;
  const int tx = threadIdx.x, ty = threadIdx.y;
  const int n = blockIdx.x * 32 + tx;
  const int k = blockIdx.y * 32 + ty;
#pragma unroll
  for (int i = 0; i < 32; i += 8)
    tile[ty + i][tx] = W[(size_t)(k + i) * DIM + n];
  __syncthreads();
  const int k2 = blockIdx.y * 32 + tx;
  const int n2 = blockIdx.x * 32 + ty;
#pragma unroll
  for (int i = 0; i < 32; i += 8)
    out[(size_t)(n2 + i) * DIM + k2] = f2bf(tile[tx][ty + i]);
}

// ---------------- kernel 3: QKV GEMM ----------------
// C[16384,1024] = xb @ W   (z=0 -> qb, z=1 -> kb, z=2 -> vt transposed [b][d][s])
__global__ __launch_bounds__(256)
void k_qkv_gemm(const unsigned short* __restrict__ xb, const unsigned short* __restrict__ wt,
                unsigned short* __restrict__ qb, unsigned short* __restrict__ kb,
                unsigned short* __restrict__ vt) {
  const int tid = threadIdx.x;
  const int l = tid & 63, w = tid >> 6;
  const int lane16 = l & 15, quad = l >> 4;
  const int wm = w & 1, wn = w >> 1;
  const int m0 = blockIdx.x * 128, n0 = blockIdx.y * 128, z = blockIdx.z;
  const unsigned short* wtz = wt + (size_t)z * DIM * DIM;

  __shared__ unsigned short As[128][40];
  __shared__ unsigned short Bs[128][40];

  f32x4 acc[4][4];
#pragma unroll
  for (int i = 0; i < 4; ++i)
#pragma unroll
    for (int j = 0; j < 4; ++j) acc[i][j] = (f32x4){0.f, 0.f, 0.f, 0.f};

  for (int k0 = 0; k0 < DIM; k0 += 32) {
#pragma unroll
    for (int i = 0; i < 2; ++i) {
      int c = tid + i * 256;
      int row = c >> 2, cc = (c & 3) * 8;
      *(bh8*)&As[row][cc] = *(const bh8*)(xb  + (size_t)(m0 + row) * DIM + k0 + cc);
      *(bh8*)&Bs[row][cc] = *(const bh8*)(wtz + (size_t)(n0 + row) * DIM + k0 + cc);
    }
    __syncthreads();
    bh8 a[4], b[4];
#pragma unroll
    for (int mt = 0; mt < 4; ++mt) a[mt] = *(const bh8*)&As[wm * 64 + mt * 16 + lane16][quad * 8];
#pragma unroll
    for (int nt = 0; nt < 4; ++nt) b[nt] = *(const bh8*)&Bs[wn * 64 + nt * 16 + lane16][quad * 8];
#pragma unroll
    for (int mt = 0; mt < 4; ++mt)
#pragma unroll
      for (int nt = 0; nt < 4; ++nt)
        acc[mt][nt] = __builtin_amdgcn_mfma_f32_16x16x32_bf16(a[mt], b[nt], acc[mt][nt], 0, 0, 0);
    __syncthreads();
  }

  if (z < 2) {
    unsigned short* outp = (z == 0) ? qb : kb;
#pragma unroll
    for (int mt = 0; mt < 4; ++mt)
#pragma unroll
      for (int nt = 0; nt < 4; ++nt) {
        int row = m0 + wm * 64 + mt * 16 + quad * 4;
        int col = n0 + wn * 64 + nt * 16 + lane16;
#pragma unroll
        for (int r = 0; r < 4; ++r)
          outp[(size_t)(row + r) * DIM + col] = f2bf(acc[mt][nt][r]);
      }
  } else {
#pragma unroll
    for (int mt = 0; mt < 4; ++mt)
#pragma unroll
      for (int nt = 0; nt < 4; ++nt) {
        int m = m0 + wm * 64 + mt * 16 + quad * 4;
        int bb = m >> 12, s = m & (SEQ - 1);
        int col = n0 + wn * 64 + nt * 16 + lane16;
        unsigned long long pk =
            (unsigned long long)f2bf(acc[mt][nt][0]) |
            ((unsigned long long)f2bf(acc[mt][nt][1]) << 16) |
            ((unsigned long long)f2bf(acc[mt][nt][2]) << 32) |
            ((unsigned long long)f2bf(acc[mt][nt][3]) << 48);
        *(unsigned long long*)(vt + (size_t)bb * DIM * SEQ + (size_t)col * SEQ + s) = pk;
      }
  }
}

// ---------------- kernel 4: causal flash attention (v2) ----------------
// 8 waves; QK^T: wave w computes partial scores over D-slice [w*128,(w+1)*128)
// for the full 32x64 tile into its OWN LDS buffer (no atomics); softmax threads
// sum the 8 copies. PV: wave w owns output-D slice [w*128,..). K/V loads
// software-pipelined across iterations.
__global__ __launch_bounds__(512, 2)
void k_attn(const unsigned short* __restrict__ qb, const unsigned short* __restrict__ kb,
            const unsigned short* __restrict__ vt, float* __restrict__ out) {
  const int tid = threadIdx.x;
  const int w = tid >> 6;
  const int l = tid & 63;
  const int lane16 = l & 15, quad = l >> 4;
  const int batch = blockIdx.x;   // batch on fast grid dim -> XCD affinity
  const int pid = blockIdx.y;     // 0..63

  // stride 68 floats: b32 partial writes 2-way (free), b128 reduce reads uniform
  __shared__ float Pp[8][32][68];          // 69.6 KB per-wave partial scores
  __shared__ unsigned short Psh[32][72];   // P in bf16 for PV A-frags
  __shared__ float row_m[32], row_l[32], row_alpha[32];

  const size_t bbase = (size_t)batch * SEQ;
  const unsigned short* vtb = vt + (size_t)batch * DIM * SEQ;
  const float cexp = 0.04508422002778f;  // log2(e)/sqrt(1024)

  for (int half = 0; half < 2; ++half) {
    const int t = (half == 0) ? pid : (127 - pid);
    const int q0 = t * 32;

    // Q fragments for this wave's D slice (held for the whole k-loop)
    bh8 qf[2][4];
#pragma unroll
    for (int mt = 0; mt < 2; ++mt)
#pragma unroll
      for (int c = 0; c < 4; ++c)
        qf[mt][c] = *(const bh8*)(qb + (bbase + q0 + mt * 16 + lane16) * DIM +
                                  w * 128 + c * 32 + quad * 8);

    f32x4 o[2][8];
#pragma unroll
    for (int mt = 0; mt < 2; ++mt)
#pragma unroll
      for (int nt = 0; nt < 8; ++nt) o[mt][nt] = (f32x4){0.f, 0.f, 0.f, 0.f};

    const int nk = (q0 + 95) >> 6;  // ceil((q0+32)/64)

    // prefetch K fragments for it=0
    bh8 kf[4][4];
#pragma unroll
    for (int kt = 0; kt < 4; ++kt)
#pragma unroll
      for (int c = 0; c < 4; ++c)
        kf[kt][c] = *(const bh8*)(kb + (bbase + kt * 16 + lane16) * DIM +
                                  w * 128 + c * 32 + quad * 8);

    for (int it = 0; it < nk; ++it) {
      const int k0 = it * 64;

      // V first half (nt 0..3) issued early — hides behind QK + softmax
      bh8 vfa[4][2];
#pragma unroll
      for (int nt = 0; nt < 4; ++nt)
#pragma unroll
        for (int kc = 0; kc < 2; ++kc)
          vfa[nt][kc] = *(const bh8*)(vtb + (size_t)(w * 128 + nt * 16 + lane16) * SEQ +
                                      k0 + kc * 32 + quad * 8);

      if (it == 0 && tid < 32) { row_m[tid] = -3.0e38f; row_l[tid] = 0.f; }

      // QK^T partials -> this wave's Pp region (no atomics)
#pragma unroll
      for (int kt = 0; kt < 4; ++kt) {
        if (k0 + kt * 16 <= q0 + 31) {  // uniform causal skip
#pragma unroll
          for (int mt = 0; mt < 2; ++mt) {
            f32x4 s = (f32x4){0.f, 0.f, 0.f, 0.f};
#pragma unroll
            for (int c = 0; c < 4; ++c)
              s = __builtin_amdgcn_mfma_f32_16x16x32_bf16(qf[mt][c], kf[kt][c], s, 0, 0, 0);
            int row = mt * 16 + quad * 4;
            int col = kt * 16 + lane16;
#pragma unroll
            for (int r = 0; r < 4; ++r)
              Pp[w][row + r][col] = s[r];
          }
        }
      }

      // prefetch K for next iteration (after last kf use; WAR-safe)
      if (it + 1 < nk) {
#pragma unroll
        for (int kt = 0; kt < 4; ++kt)
#pragma unroll
          for (int c = 0; c < 4; ++c)
            kf[kt][c] = *(const bh8*)(kb + (bbase + k0 + 64 + kt * 16 + lane16) * DIM +
                                      w * 128 + c * 32 + quad * 8);
      }
      __syncthreads();  // (1) partials visible

      // reduce 8 partials + online softmax; thread -> (row=tid>>4, cols=(tid&15)*4..+3)
      {
        int r = tid >> 4, c0 = (tid & 15) * 4;
        int q = q0 + r;
        f32x4 sv = *(const f32x4*)&Pp[0][r][c0];
#pragma unroll
        for (int ww = 1; ww < 8; ++ww)
          sv += *(const f32x4*)&Pp[ww][r][c0];
#pragma unroll
        for (int j = 0; j < 4; ++j)
          if (k0 + c0 + j > q) sv[j] = -3.0e38f;
        float mx = fmaxf(fmaxf(sv[0], sv[1]), fmaxf(sv[2], sv[3]));
#pragma unroll
        for (int off = 1; off < 16; off <<= 1)
          mx = fmaxf(mx, __shfl_xor(mx, off));
        float mold = row_m[r];
        float mnew = fmaxf(mold, mx);
        float p0 = __builtin_amdgcn_exp2f((sv[0] - mnew) * cexp);
        float p1 = __builtin_amdgcn_exp2f((sv[1] - mnew) * cexp);
        float p2 = __builtin_amdgcn_exp2f((sv[2] - mnew) * cexp);
        float p3 = __builtin_amdgcn_exp2f((sv[3] - mnew) * cexp);
        float sum = (p0 + p1) + (p2 + p3);
#pragma unroll
        for (int off = 1; off < 16; off <<= 1)
          sum += __shfl_xor(sum, off);
        float alpha = __builtin_amdgcn_exp2f((mold - mnew) * cexp);
        u32x2 pk;
        pk[0] = (unsigned)f2bf(p0) | ((unsigned)f2bf(p1) << 16);
        pk[1] = (unsigned)f2bf(p2) | ((unsigned)f2bf(p3) << 16);
        *(u32x2*)&Psh[r][c0] = pk;
        if ((tid & 15) == 0) {
          row_m[r] = mnew;
          row_l[r] = alpha * row_l[r] + sum;
          row_alpha[r] = alpha;
        }
      }
      __syncthreads();  // (2) Psh / row_alpha visible

      // PV over this wave's 128 output columns
      {
        // V second half (nt 4..7) issued now — hides behind first-half MFMA
        bh8 vfb[4][2];
#pragma unroll
        for (int nt = 0; nt < 4; ++nt)
#pragma unroll
          for (int kc = 0; kc < 2; ++kc)
            vfb[nt][kc] = *(const bh8*)(vtb + (size_t)(w * 128 + (nt + 4) * 16 + lane16) * SEQ +
                                        k0 + kc * 32 + quad * 8);

#pragma unroll
        for (int mt = 0; mt < 2; ++mt) {
          f32x4 al;
#pragma unroll
          for (int r = 0; r < 4; ++r) al[r] = row_alpha[mt * 16 + quad * 4 + r];
#pragma unroll
          for (int nt = 0; nt < 8; ++nt) o[mt][nt] *= al;
        }
        bh8 pf[2][2];
#pragma unroll
        for (int mt = 0; mt < 2; ++mt)
#pragma unroll
          for (int kc = 0; kc < 2; ++kc)
            pf[mt][kc] = *(const bh8*)&Psh[mt * 16 + lane16][kc * 32 + quad * 8];
#pragma unroll
        for (int kc = 0; kc < 2; ++kc) {
          if (k0 + kc * 32 <= q0 + 31) {  // beyond-diag P block is all-zero
#pragma unroll
            for (int nt = 0; nt < 4; ++nt)
#pragma unroll
              for (int mt = 0; mt < 2; ++mt)
                o[mt][nt] = __builtin_amdgcn_mfma_f32_16x16x32_bf16(pf[mt][kc], vfa[nt][kc], o[mt][nt], 0, 0, 0);
#pragma unroll
            for (int nt = 0; nt < 4; ++nt)
#pragma unroll
              for (int mt = 0; mt < 2; ++mt)
                o[mt][nt + 4] = __builtin_amdgcn_mfma_f32_16x16x32_bf16(pf[mt][kc], vfb[nt][kc], o[mt][nt + 4], 0, 0, 0);
          }
        }
      }
      // no barrier here: Pp(i+1) vs softmax-reads(i) split by barrier (2);
      // Psh-writes(i+1) vs PV-reads(i) split by barrier (1) of i+1.
    }

    // epilogue: O / l -> fp32 out
#pragma unroll
    for (int mt = 0; mt < 2; ++mt) {
      int row = mt * 16 + quad * 4;
      float il[4];
#pragma unroll
      for (int r = 0; r < 4; ++r) il[r] = 1.0f / row_l[row + r];
#pragma unroll
      for (int nt = 0; nt < 8; ++nt) {
        size_t base = (bbase + q0 + row) * DIM + w * 128 + nt * 16 + lane16;
#pragma unroll
        for (int r = 0; r < 4; ++r)
          out[base + (size_t)r * DIM] = o[mt][nt][r] * il[r];
      }
    }
    __syncthreads();  // protect row_m/l/Pp before next half
  }
}

// ---------------- launch ----------------
extern "C" void kernel_launch(void* const* d_in, const int* in_sizes, int n_in,
                              void* d_out, int out_size, void* d_ws, size_t ws_size,
                              hipStream_t stream) {
  const float* x  = (const float*)d_in[0];
  const float* Wq = (const float*)d_in[1];
  const float* Wk = (const float*)d_in[2];
  const float* Wv = (const float*)d_in[3];
  float* out = (float*)d_out;

  char* ws = (char*)d_ws;
  const size_t XB_BYTES = (size_t)MTOT * DIM * 2;        // 32 MB
  const size_t WT_BYTES = (size_t)3 * DIM * DIM * 2;     // 6 MB
  unsigned short* xb = (unsigned short*)(ws);
  unsigned short* wt = (unsigned short*)(ws + XB_BYTES);
  unsigned short* qb = (unsigned short*)(ws + XB_BYTES + WT_BYTES);
  unsigned short* kb = qb + (size_t)MTOT * DIM;
  unsigned short* vt = kb + (size_t)MTOT * DIM;

  k_convert_x<<<dim3((MTOT * DIM) / (256 * 8)), dim3(256), 0, stream>>>(x, xb);
  k_transpose_w<<<dim3(32, 32, 3), dim3(32, 8), 0, stream>>>(Wq, Wk, Wv, wt);
  k_qkv_gemm<<<dim3(MTOT / 128, DIM / 128, 3), dim3(256), 0, stream>>>(xb, wt, qb, kb, vt);
  k_attn<<<dim3(BATCH, 64), dim3(512), 0, stream>>>(qb, kb, vt, out);
}